// Round 5
// baseline (313.939 us; speedup 1.0000x reference)
//
#include <hip/hip_runtime.h>
#include <math.h>

#define NSCALE 0.44668359215096315f

__device__ __forceinline__ float eluf(float v)  { return v > 0.0f ? v : __expf(v) - 1.0f; }
__device__ __forceinline__ float reluf(float v) { return fmaxf(v, 0.0f); }

// ---------------- kA: encoder -> z (stored to ws), per-block partial sums ----------------
__global__ __launch_bounds__(256) void kA(const float* __restrict__ x,
                                          const float* __restrict__ ew1, const float* __restrict__ eb1,
                                          const float* __restrict__ ew2, const float* __restrict__ eb2,
                                          float* __restrict__ partials, float* __restrict__ zout, int B)
{
    __shared__ float wsum[4][32];
    int tid = threadIdx.x;
    int i = blockIdx.x * 256 + tid;
    bool valid = i < B;
    float xv[16];
    if (valid) {
        const float4* xp = reinterpret_cast<const float4*>(x + (size_t)i * 16);
#pragma unroll
        for (int q = 0; q < 4; ++q) {
            float4 v = xp[q];
            xv[4*q+0] = v.x; xv[4*q+1] = v.y; xv[4*q+2] = v.z; xv[4*q+3] = v.w;
        }
    } else {
#pragma unroll
        for (int q = 0; q < 16; ++q) xv[q] = 0.0f;
    }

    float h1[16];
#pragma unroll
    for (int o = 0; o < 16; ++o) {
        float a = eb1[o];
#pragma unroll
        for (int k = 0; k < 16; ++k) a = fmaf(xv[k], ew1[o*16+k], a);
        h1[o] = eluf(a);
    }
    float z[16];
#pragma unroll
    for (int o = 0; o < 16; ++o) {
        float a = eb2[o];
#pragma unroll
        for (int k = 0; k < 16; ++k) a = fmaf(h1[k], ew2[o*16+k], a);
        z[o] = valid ? a : 0.0f;
    }

    if (valid) {
        float4* zp = reinterpret_cast<float4*>(zout + (size_t)i * 16);
        zp[0] = make_float4(z[0],  z[1],  z[2],  z[3]);
        zp[1] = make_float4(z[4],  z[5],  z[6],  z[7]);
        zp[2] = make_float4(z[8],  z[9],  z[10], z[11]);
        zp[3] = make_float4(z[12], z[13], z[14], z[15]);
    }

    int lane = tid & 63, wave = tid >> 6;
#pragma unroll
    for (int c = 0; c < 16; ++c) {
        float s = z[c];
        float q = z[c] * z[c];
#pragma unroll
        for (int m = 1; m < 64; m <<= 1) { s += __shfl_xor(s, m); q += __shfl_xor(q, m); }
        if (lane == 0) { wsum[wave][c] = s; wsum[wave][16 + c] = q; }
    }
    __syncthreads();
    if (tid < 32) {
        float t = wsum[0][tid] + wsum[1][tid] + wsum[2][tid] + wsum[3][tid];
        partials[(size_t)blockIdx.x * 32 + tid] = t;
    }
}

// ---------------- kB: reduce partials -> BN affine ----------------
__global__ __launch_bounds__(256) void kB(const float* __restrict__ partials, int nblk, int B,
                                          const float* __restrict__ bng, const float* __restrict__ bnb,
                                          float* __restrict__ bnp)
{
    int tid = threadIdx.x;
    int q = tid >> 3, k = tid & 7;
    int chunk = (nblk + 7) / 8;
    int j0 = k * chunk;
    int j1 = j0 + chunk; if (j1 > nblk) j1 = nblk;
    double s = 0.0;
    for (int j = j0; j < j1; ++j) s += (double)partials[(size_t)j * 32 + q];
    s += __shfl_xor(s, 4);
    s += __shfl_xor(s, 2);
    s += __shfl_xor(s, 1);
    __shared__ double tot[32];
    if (k == 0) tot[q] = s;
    __syncthreads();
    if (tid < 16) {
        double mu  = tot[tid] / (double)B;
        double var = tot[16 + tid] / (double)B - mu * mu;
        double a = (double)bng[tid] / sqrt(var + 1e-5);
        double b = (double)bnb[tid] - mu * a;
        bnp[tid]      = (float)a;
        bnp[16 + tid] = (float)b;
    }
}

// ---------------- k1: BN + FIR + noise, in-place z -> cr ----------------
__global__ __launch_bounds__(256) void k1(float* __restrict__ crt,
                                          const float* __restrict__ fading,
                                          const float* __restrict__ noise,
                                          const float* __restrict__ bnp, int B)
{
    int i = blockIdx.x * 256 + threadIdx.x;
    if (i >= B) return;

    float zn[16];
    {
        const float4* zp = reinterpret_cast<const float4*>(crt + (size_t)i * 16);
#pragma unroll
        for (int q = 0; q < 4; ++q) {
            float4 v = zp[q];
            zn[4*q+0] = fmaf(v.x, bnp[4*q+0], bnp[16 + 4*q+0]);
            zn[4*q+1] = fmaf(v.y, bnp[4*q+1], bnp[16 + 4*q+1]);
            zn[4*q+2] = fmaf(v.z, bnp[4*q+2], bnp[16 + 4*q+2]);
            zn[4*q+3] = fmaf(v.w, bnp[4*q+3], bnp[16 + 4*q+3]);
        }
    }
    float f[6];
    {
        const float2* fp = reinterpret_cast<const float2*>(fading + (size_t)i * 6);
#pragma unroll
        for (int q = 0; q < 3; ++q) { float2 v = fp[q]; f[2*q] = v.x; f[2*q+1] = v.y; }
    }
    float cr[16];
#pragma unroll
    for (int n = 0; n < 8; ++n) {
        float re = f[0]*zn[2*n]   - f[1]*zn[2*n+1];
        float im = f[0]*zn[2*n+1] + f[1]*zn[2*n];
        if (n >= 1) { re += f[2]*zn[2*n-2] - f[3]*zn[2*n-1];
                      im += f[2]*zn[2*n-1] + f[3]*zn[2*n-2]; }
        if (n >= 2) { re += f[4]*zn[2*n-4] - f[5]*zn[2*n-3];
                      im += f[4]*zn[2*n-3] + f[5]*zn[2*n-4]; }
        cr[2*n] = re; cr[2*n+1] = im;
    }
    {
        const float4* np_ = reinterpret_cast<const float4*>(noise + (size_t)i * 16);
#pragma unroll
        for (int q = 0; q < 4; ++q) {
            float4 v = np_[q];
            cr[4*q+0] = fmaf(v.x, NSCALE, cr[4*q+0]);
            cr[4*q+1] = fmaf(v.y, NSCALE, cr[4*q+1]);
            cr[4*q+2] = fmaf(v.z, NSCALE, cr[4*q+2]);
            cr[4*q+3] = fmaf(v.w, NSCALE, cr[4*q+3]);
        }
    }
    float4* op = reinterpret_cast<float4*>(crt + (size_t)i * 16);
    op[0] = make_float4(cr[0],  cr[1],  cr[2],  cr[3]);
    op[1] = make_float4(cr[4],  cr[5],  cr[6],  cr[7]);
    op[2] = make_float4(cr[8],  cr[9],  cr[10], cr[11]);
    op[3] = make_float4(cr[12], cr[13], cr[14], cr[15]);
}

// ---------------- k23: p-convs + pl + equalizer, 2 elements/thread, tr in-place ----------------
__global__ __launch_bounds__(256) void k23(float* __restrict__ crt,
    const float* __restrict__ pc1w, const float* __restrict__ pc1b,
    const float* __restrict__ pc2w, const float* __restrict__ pc2b,
    const float* __restrict__ pc3w, const float* __restrict__ pc3b,
    const float* __restrict__ pc4w, const float* __restrict__ pc4b,
    const float* __restrict__ pc5w, const float* __restrict__ pc5b,
    const float* __restrict__ plw,  const float* __restrict__ plb,
    int B, int half)
{
    int t0 = blockIdx.x * 256 + threadIdx.x;
    if (t0 >= half) return;
    int iA = t0;
    int iB = t0 + half;
    bool vB = iB < B;
    if (!vB) iB = B - 1;

    float p5A[16], p5B[16];
#pragma unroll
    for (int o = 0; o < 16; ++o) { float b = pc5b[o]; p5A[o] = b; p5B[o] = b; }

#pragma unroll 1
    for (int g = 0; g < 3; ++g) {
        float cA[8], cB[8];
        {
            const float4* pA = reinterpret_cast<const float4*>(crt + (size_t)iA * 16 + 4 * g);
            float4 a0 = pA[0], a1 = pA[1];
            cA[0]=a0.x; cA[1]=a0.y; cA[2]=a0.z; cA[3]=a0.w;
            cA[4]=a1.x; cA[5]=a1.y; cA[6]=a1.z; cA[7]=a1.w;
            const float4* pB = reinterpret_cast<const float4*>(crt + (size_t)iB * 16 + 4 * g);
            float4 b0 = pB[0], b1 = pB[1];
            cB[0]=b0.x; cB[1]=b0.y; cB[2]=b0.z; cB[3]=b0.w;
            cB[4]=b1.x; cB[5]=b1.y; cB[6]=b1.z; cB[7]=b1.w;
        }
        float q0A[16], q0B[16], q1A[16], q1B[16];
#pragma unroll
        for (int o = 0; o < 16; ++o) {
            float b = pc2b[o];
            q0A[o]=b; q0B[o]=b; q1A[o]=b; q1B[o]=b;
        }

        // ---- t-step 0: p1(col0) -> q0 via tap0 ----
        {
            float p1A[16], p1B[16];
#pragma unroll
            for (int o = 0; o < 16; ++o) {
                float aA = pc1b[o], aB = aA;
#pragma unroll
                for (int k = 0; k < 4; ++k) { float w = pc1w[o*4+k]; aA = fmaf(w, cA[0+k], aA); aB = fmaf(w, cB[0+k], aB); }
                p1A[o] = reluf(aA); p1B[o] = reluf(aB);
            }
#pragma unroll
            for (int o = 0; o < 16; ++o) {
                float aA = q0A[o], aB = q0B[o];
#pragma unroll
                for (int ci = 0; ci < 16; ++ci) { float w = pc2w[o*32+ci*2+0]; aA = fmaf(w, p1A[ci], aA); aB = fmaf(w, p1B[ci], aB); }
                q0A[o] = aA; q0B[o] = aB;
            }
        }
        // ---- t-step 1: p1(col1) -> q1 via tap0, q0 via tap1 ----
        {
            float p1A[16], p1B[16];
#pragma unroll
            for (int o = 0; o < 16; ++o) {
                float aA = pc1b[o], aB = aA;
#pragma unroll
                for (int k = 0; k < 4; ++k) { float w = pc1w[o*4+k]; aA = fmaf(w, cA[1+k], aA); aB = fmaf(w, cB[1+k], aB); }
                p1A[o] = reluf(aA); p1B[o] = reluf(aB);
            }
#pragma unroll
            for (int o = 0; o < 16; ++o) {
                float a0A = q0A[o], a0B = q0B[o], a1A = q1A[o], a1B = q1B[o];
#pragma unroll
                for (int ci = 0; ci < 16; ++ci) {
                    float w0 = pc2w[o*32+ci*2+0], w1 = pc2w[o*32+ci*2+1];
                    a1A = fmaf(w0, p1A[ci], a1A); a1B = fmaf(w0, p1B[ci], a1B);
                    a0A = fmaf(w1, p1A[ci], a0A); a0B = fmaf(w1, p1B[ci], a0B);
                }
                q0A[o] = a0A; q0B[o] = a0B; q1A[o] = a1A; q1B[o] = a1B;
            }
        }
        // ---- t-step 2: p1(col2) -> q1 via tap1 ----
        {
            float p1A[16], p1B[16];
#pragma unroll
            for (int o = 0; o < 16; ++o) {
                float aA = pc1b[o], aB = aA;
#pragma unroll
                for (int k = 0; k < 4; ++k) { float w = pc1w[o*4+k]; aA = fmaf(w, cA[2+k], aA); aB = fmaf(w, cB[2+k], aB); }
                p1A[o] = reluf(aA); p1B[o] = reluf(aB);
            }
#pragma unroll
            for (int o = 0; o < 16; ++o) {
                float aA = q1A[o], aB = q1B[o];
#pragma unroll
                for (int ci = 0; ci < 16; ++ci) { float w = pc2w[o*32+ci*2+1]; aA = fmaf(w, p1A[ci], aA); aB = fmaf(w, p1B[ci], aB); }
                q1A[o] = aA; q1B[o] = aB;
            }
        }
#pragma unroll
        for (int o = 0; o < 16; ++o) {
            q0A[o] = reluf(q0A[o]); q0B[o] = reluf(q0B[o]);
            q1A[o] = reluf(q1A[o]); q1B[o] = reluf(q1B[o]);
        }

        // ---- p3 ----
        float r3A[16], r3B[16];
#pragma unroll
        for (int o = 0; o < 16; ++o) {
            float aA = pc3b[o], aB = aA;
#pragma unroll
            for (int ci = 0; ci < 16; ++ci) {
                float w0 = pc3w[o*32+ci*2+0], w1 = pc3w[o*32+ci*2+1];
                aA = fmaf(w0, q0A[ci], aA); aA = fmaf(w1, q1A[ci], aA);
                aB = fmaf(w0, q0B[ci], aB); aB = fmaf(w1, q1B[ci], aB);
            }
            r3A[o] = reluf(aA); r3B[o] = reluf(aB);
        }
        // ---- p4 ----
        float r4A[16], r4B[16];
#pragma unroll
        for (int o = 0; o < 16; ++o) {
            float aA = pc4b[o], aB = aA;
#pragma unroll
            for (int ci = 0; ci < 16; ++ci) { float w = pc4w[o*16+ci]; aA = fmaf(w, r3A[ci], aA); aB = fmaf(w, r3B[ci], aB); }
            r4A[o] = reluf(aA); r4B[o] = reluf(aB);
        }
        // ---- p5 accumulate (runtime g on global pointer: OK) ----
#pragma unroll
        for (int o = 0; o < 16; ++o) {
            float aA = p5A[o], aB = p5B[o];
#pragma unroll
            for (int ci = 0; ci < 16; ++ci) { float w = pc5w[o*48+ci*3+g]; aA = fmaf(w, r4A[ci], aA); aB = fmaf(w, r4B[ci], aB); }
            p5A[o] = aA; p5B[o] = aB;
        }
    }

    // ---- pl ----
    float p5rA[16], p5rB[16];
#pragma unroll
    for (int o = 0; o < 16; ++o) { p5rA[o] = reluf(p5A[o]); p5rB[o] = reluf(p5B[o]); }
    float hA[16], hB[16];
#pragma unroll
    for (int o = 0; o < 16; ++o) {
        float aA = plb[o], aB = aA;
#pragma unroll
        for (int ci = 0; ci < 16; ++ci) { float w = plw[o*16+ci]; aA = fmaf(w, p5rA[ci], aA); aB = fmaf(w, p5rB[ci], aB); }
        hA[o] = aA; hB[o] = aB;
    }

    // ---- equalizer ----
    float crA[16], crB[16];
    {
        const float4* pA = reinterpret_cast<const float4*>(crt + (size_t)iA * 16);
#pragma unroll
        for (int q = 0; q < 4; ++q) { float4 v = pA[q]; crA[4*q+0]=v.x; crA[4*q+1]=v.y; crA[4*q+2]=v.z; crA[4*q+3]=v.w; }
        const float4* pB = reinterpret_cast<const float4*>(crt + (size_t)iB * 16);
#pragma unroll
        for (int q = 0; q < 4; ++q) { float4 v = pB[q]; crB[4*q+0]=v.x; crB[4*q+1]=v.y; crB[4*q+2]=v.z; crB[4*q+3]=v.w; }
    }
    float trA[16], trB[16];
#pragma unroll
    for (int n = 0; n < 8; ++n) {
        {
            float a = crA[2*n], b = crA[2*n+1];
            float c = hA[2*n],  d = hA[2*n+1];
            float inv = 1.0f / (c*c + d*d);
            trA[2*n]   = (a*c + b*d) * inv;
            trA[2*n+1] = (b*c - a*d) * inv;
        }
        {
            float a = crB[2*n], b = crB[2*n+1];
            float c = hB[2*n],  d = hB[2*n+1];
            float inv = 1.0f / (c*c + d*d);
            trB[2*n]   = (a*c + b*d) * inv;
            trB[2*n+1] = (b*c - a*d) * inv;
        }
    }
    {
        float4* op = reinterpret_cast<float4*>(crt + (size_t)iA * 16);
        op[0] = make_float4(trA[0],  trA[1],  trA[2],  trA[3]);
        op[1] = make_float4(trA[4],  trA[5],  trA[6],  trA[7]);
        op[2] = make_float4(trA[8],  trA[9],  trA[10], trA[11]);
        op[3] = make_float4(trA[12], trA[13], trA[14], trA[15]);
    }
    if (vB) {
        float4* op = reinterpret_cast<float4*>(crt + (size_t)iB * 16);
        op[0] = make_float4(trB[0],  trB[1],  trB[2],  trB[3]);
        op[1] = make_float4(trB[4],  trB[5],  trB[6],  trB[7]);
        op[2] = make_float4(trB[8],  trB[9],  trB[10], trB[11]);
        op[3] = make_float4(trB[12], trB[13], trB[14], trB[15]);
    }
}

// ---------------- k4: d-convs + dl1/dl2/dl3, 2 elements/thread ----------------
__global__ __launch_bounds__(256) void k4(const float* __restrict__ trt,
    const float* __restrict__ dc1w, const float* __restrict__ dc1b,
    const float* __restrict__ dc2w, const float* __restrict__ dc2b,
    const float* __restrict__ dc3w, const float* __restrict__ dc3b,
    const float* __restrict__ dc4w, const float* __restrict__ dc4b,
    const float* __restrict__ dl1w, const float* __restrict__ dl1b,
    const float* __restrict__ dl2w, const float* __restrict__ dl2b,
    const float* __restrict__ dl3w, const float* __restrict__ dl3b,
    float* __restrict__ out, int B, int half)
{
    int t0 = blockIdx.x * 256 + threadIdx.x;
    if (t0 >= half) return;
    int iA = t0;
    int iB = t0 + half;
    bool vB = iB < B;
    if (!vB) iB = B - 1;

    float yA[16], yB[16];
#pragma unroll
    for (int o = 0; o < 16; ++o) { float b = dl1b[o]; yA[o] = b; yB[o] = b; }

#pragma unroll 1
    for (int t = 0; t < 8; ++t) {
        float2 tvA = *reinterpret_cast<const float2*>(trt + (size_t)iA * 16 + 2 * t);
        float2 tvB = *reinterpret_cast<const float2*>(trt + (size_t)iB * 16 + 2 * t);
        float d1aA[8], d1bA[8], d1aB[8], d1bB[8];
#pragma unroll
        for (int c = 0; c < 8; ++c) {
            float w = dc1w[c], b = dc1b[c];
            d1aA[c] = reluf(fmaf(w, tvA.x, b));
            d1bA[c] = reluf(fmaf(w, tvA.y, b));
            d1aB[c] = reluf(fmaf(w, tvB.x, b));
            d1bB[c] = reluf(fmaf(w, tvB.y, b));
        }
        float d2A[8], d2B[8];
#pragma unroll
        for (int c = 0; c < 8; ++c) {
            float aA = dc2b[c], aB = aA;
#pragma unroll
            for (int ci = 0; ci < 8; ++ci) {
                float w0 = dc2w[c*16+ci*2+0], w1 = dc2w[c*16+ci*2+1];
                aA = fmaf(w0, d1aA[ci], aA); aA = fmaf(w1, d1bA[ci], aA);
                aB = fmaf(w0, d1aB[ci], aB); aB = fmaf(w1, d1bB[ci], aB);
            }
            d2A[c] = reluf(aA); d2B[c] = reluf(aB);
        }
        float d3A[8], d3B[8];
#pragma unroll
        for (int c = 0; c < 8; ++c) {
            float aA = dc3b[c], aB = aA;
#pragma unroll
            for (int ci = 0; ci < 8; ++ci) { float w = dc3w[c*8+ci]; aA = fmaf(w, d2A[ci], aA); aB = fmaf(w, d2B[ci], aB); }
            d3A[c] = reluf(aA); d3B[c] = reluf(aB);
        }
        float d4A[8], d4B[8];
#pragma unroll
        for (int c = 0; c < 8; ++c) {
            float aA = dc4b[c], aB = aA;
#pragma unroll
            for (int ci = 0; ci < 8; ++ci) { float w = dc4w[c*8+ci]; aA = fmaf(w, d3A[ci], aA); aB = fmaf(w, d3B[ci], aB); }
            d4A[c] = reluf(aA); d4B[c] = reluf(aB);
        }
#pragma unroll
        for (int o = 0; o < 16; ++o) {
            float aA = yA[o], aB = yB[o];
#pragma unroll
            for (int c = 0; c < 8; ++c) { float w = dl1w[o*64 + c*8 + t]; aA = fmaf(w, d4A[c], aA); aB = fmaf(w, d4B[c], aB); }
            yA[o] = aA; yB[o] = aB;
        }
    }
#pragma unroll
    for (int o = 0; o < 16; ++o) { yA[o] = reluf(yA[o]); yB[o] = reluf(yB[o]); }
    float h2A[16], h2B[16];
#pragma unroll
    for (int o = 0; o < 16; ++o) {
        float aA = dl2b[o], aB = aA;
#pragma unroll
        for (int ci = 0; ci < 16; ++ci) { float w = dl2w[o*16+ci]; aA = fmaf(w, yA[ci], aA); aB = fmaf(w, yB[ci], aB); }
        h2A[o] = eluf(aA); h2B[o] = eluf(aB);
    }
    float oA[16], oB[16];
#pragma unroll
    for (int o = 0; o < 16; ++o) {
        float aA = dl3b[o], aB = aA;
#pragma unroll
        for (int ci = 0; ci < 16; ++ci) { float w = dl3w[o*16+ci]; aA = fmaf(w, h2A[ci], aA); aB = fmaf(w, h2B[ci], aB); }
        oA[o] = aA; oB[o] = aB;
    }
    {
        float4* op = reinterpret_cast<float4*>(out + (size_t)iA * 16);
        op[0] = make_float4(oA[0],  oA[1],  oA[2],  oA[3]);
        op[1] = make_float4(oA[4],  oA[5],  oA[6],  oA[7]);
        op[2] = make_float4(oA[8],  oA[9],  oA[10], oA[11]);
        op[3] = make_float4(oA[12], oA[13], oA[14], oA[15]);
    }
    if (vB) {
        float4* op = reinterpret_cast<float4*>(out + (size_t)iB * 16);
        op[0] = make_float4(oB[0],  oB[1],  oB[2],  oB[3]);
        op[1] = make_float4(oB[4],  oB[5],  oB[6],  oB[7]);
        op[2] = make_float4(oB[8],  oB[9],  oB[10], oB[11]);
        op[3] = make_float4(oB[12], oB[13], oB[14], oB[15]);
    }
}

extern "C" void kernel_launch(void* const* d_in, const int* in_sizes, int n_in,
                              void* d_out, int out_size, void* d_ws, size_t ws_size,
                              hipStream_t stream)
{
    const float* x      = (const float*)d_in[0];
    const float* noise  = (const float*)d_in[1];
    const float* fading = (const float*)d_in[2];
    const float* ew1  = (const float*)d_in[3];
    const float* eb1  = (const float*)d_in[4];
    const float* ew2  = (const float*)d_in[5];
    const float* eb2  = (const float*)d_in[6];
    const float* bng  = (const float*)d_in[7];
    const float* bnb  = (const float*)d_in[8];
    const float* pc1w = (const float*)d_in[9];
    const float* pc1b = (const float*)d_in[10];
    const float* pc2w = (const float*)d_in[11];
    const float* pc2b = (const float*)d_in[12];
    const float* pc3w = (const float*)d_in[13];
    const float* pc3b = (const float*)d_in[14];
    const float* pc4w = (const float*)d_in[15];
    const float* pc4b = (const float*)d_in[16];
    const float* pc5w = (const float*)d_in[17];
    const float* pc5b = (const float*)d_in[18];
    const float* plw  = (const float*)d_in[19];
    const float* plb  = (const float*)d_in[20];
    const float* dc1w = (const float*)d_in[21];
    const float* dc1b = (const float*)d_in[22];
    const float* dc2w = (const float*)d_in[23];
    const float* dc2b = (const float*)d_in[24];
    const float* dc3w = (const float*)d_in[25];
    const float* dc3b = (const float*)d_in[26];
    const float* dc4w = (const float*)d_in[27];
    const float* dc4b = (const float*)d_in[28];
    const float* dl1w = (const float*)d_in[29];
    const float* dl1b = (const float*)d_in[30];
    const float* dl2w = (const float*)d_in[31];
    const float* dl2b = (const float*)d_in[32];
    const float* dl3w = (const float*)d_in[33];
    const float* dl3b = (const float*)d_in[34];

    int B = in_sizes[0] / 16;
    int nblk = (B + 255) / 256;
    int half = (B + 1) / 2;
    int nblk2 = (half + 255) / 256;

    float* partials = (float*)d_ws;                 // nblk*32 floats
    float* bnp = partials + (size_t)nblk * 32;      // 32 floats
    float* crt = bnp + 32;                          // B*16 floats (z -> cr -> tr in-place)

    kA<<<nblk, 256, 0, stream>>>(x, ew1, eb1, ew2, eb2, partials, crt, B);
    kB<<<1, 256, 0, stream>>>(partials, nblk, B, bng, bnb, bnp);
    k1<<<nblk, 256, 0, stream>>>(crt, fading, noise, bnp, B);
    k23<<<nblk2, 256, 0, stream>>>(crt,
                                   pc1w, pc1b, pc2w, pc2b, pc3w, pc3b, pc4w, pc4b, pc5w, pc5b,
                                   plw, plb, B, half);
    k4<<<nblk2, 256, 0, stream>>>(crt,
                                  dc1w, dc1b, dc2w, dc2b, dc3w, dc3b, dc4w, dc4b,
                                  dl1w, dl1b, dl2w, dl2b, dl3w, dl3b,
                                  (float*)d_out, B, half);
}

// Round 6
// 283.334 us; speedup vs baseline: 1.1080x; 1.1080x over previous
//
#include <hip/hip_runtime.h>
#include <math.h>

#define NSCALE 0.44668359215096315f

__device__ __forceinline__ float eluf(float v)  { return v > 0.0f ? v : __expf(v) - 1.0f; }
__device__ __forceinline__ float reluf(float v) { return fmaxf(v, 0.0f); }

// ---------------- kW: one-time weight swizzle into ws (consumption-order layouts) ----------------
__global__ __launch_bounds__(256) void kW(const float* __restrict__ pc2w,
                                          const float* __restrict__ pc5w,
                                          const float* __restrict__ dl1w,
                                          float* __restrict__ pc2s,
                                          float* __restrict__ pc5s,
                                          float* __restrict__ dl1s)
{
    int tid = threadIdx.x;
    for (int j = tid; j < 512; j += 256) {            // pc2w[o*32+ci*2+tap] -> [tap][o][ci]
        int o = j >> 5, r = j & 31, ci = r >> 1, tap = r & 1;
        pc2s[tap*256 + o*16 + ci] = pc2w[j];
    }
    for (int j = tid; j < 768; j += 256) {            // pc5w[o*48+ci*3+g] -> [g][o][ci]
        int o = j / 48, r = j - o*48, ci = r / 3, g = r - ci*3;
        pc5s[g*256 + o*16 + ci] = pc5w[j];
    }
    for (int j = tid; j < 1024; j += 256) {           // dl1w[o*64+c*8+t] -> [t][o][c]
        int o = j >> 6, r = j & 63, c = r >> 3, t = r & 7;
        dl1s[t*128 + o*8 + c] = dl1w[j];
    }
}

// ---------------- kA: encoder -> z (stored to ws), per-block partial sums ----------------
__global__ __launch_bounds__(256) void kA(const float* __restrict__ x,
                                          const float* __restrict__ ew1, const float* __restrict__ eb1,
                                          const float* __restrict__ ew2, const float* __restrict__ eb2,
                                          float* __restrict__ partials, float* __restrict__ zout, int B)
{
    __shared__ float wsum[4][32];
    int tid = threadIdx.x;
    int i = blockIdx.x * 256 + tid;
    bool valid = i < B;
    float xv[16];
    if (valid) {
        const float4* xp = reinterpret_cast<const float4*>(x + (size_t)i * 16);
#pragma unroll
        for (int q = 0; q < 4; ++q) {
            float4 v = xp[q];
            xv[4*q+0] = v.x; xv[4*q+1] = v.y; xv[4*q+2] = v.z; xv[4*q+3] = v.w;
        }
    } else {
#pragma unroll
        for (int q = 0; q < 16; ++q) xv[q] = 0.0f;
    }

    float h1[16];
#pragma unroll
    for (int o = 0; o < 16; ++o) {
        float a = eb1[o];
#pragma unroll
        for (int k = 0; k < 16; ++k) a = fmaf(xv[k], ew1[o*16+k], a);
        h1[o] = eluf(a);
    }
    float z[16];
#pragma unroll
    for (int o = 0; o < 16; ++o) {
        float a = eb2[o];
#pragma unroll
        for (int k = 0; k < 16; ++k) a = fmaf(h1[k], ew2[o*16+k], a);
        z[o] = valid ? a : 0.0f;
    }

    if (valid) {
        float4* zp = reinterpret_cast<float4*>(zout + (size_t)i * 16);
        zp[0] = make_float4(z[0],  z[1],  z[2],  z[3]);
        zp[1] = make_float4(z[4],  z[5],  z[6],  z[7]);
        zp[2] = make_float4(z[8],  z[9],  z[10], z[11]);
        zp[3] = make_float4(z[12], z[13], z[14], z[15]);
    }

    int lane = tid & 63, wave = tid >> 6;
#pragma unroll
    for (int c = 0; c < 16; ++c) {
        float s = z[c];
        float q = z[c] * z[c];
#pragma unroll
        for (int m = 1; m < 64; m <<= 1) { s += __shfl_xor(s, m); q += __shfl_xor(q, m); }
        if (lane == 0) { wsum[wave][c] = s; wsum[wave][16 + c] = q; }
    }
    __syncthreads();
    if (tid < 32) {
        float t = wsum[0][tid] + wsum[1][tid] + wsum[2][tid] + wsum[3][tid];
        partials[(size_t)blockIdx.x * 32 + tid] = t;
    }
}

// ---------------- kB: reduce partials -> BN affine ----------------
__global__ __launch_bounds__(256) void kB(const float* __restrict__ partials, int nblk, int B,
                                          const float* __restrict__ bng, const float* __restrict__ bnb,
                                          float* __restrict__ bnp)
{
    int tid = threadIdx.x;
    int q = tid >> 3, k = tid & 7;
    int chunk = (nblk + 7) / 8;
    int j0 = k * chunk;
    int j1 = j0 + chunk; if (j1 > nblk) j1 = nblk;
    double s = 0.0;
    for (int j = j0; j < j1; ++j) s += (double)partials[(size_t)j * 32 + q];
    s += __shfl_xor(s, 4);
    s += __shfl_xor(s, 2);
    s += __shfl_xor(s, 1);
    __shared__ double tot[32];
    if (k == 0) tot[q] = s;
    __syncthreads();
    if (tid < 16) {
        double mu  = tot[tid] / (double)B;
        double var = tot[16 + tid] / (double)B - mu * mu;
        double a = (double)bng[tid] / sqrt(var + 1e-5);
        double b = (double)bnb[tid] - mu * a;
        bnp[tid]      = (float)a;
        bnp[16 + tid] = (float)b;
    }
}

// ---------------- k23: BN+FIR+noise fused, p-convs + pl + equalizer; tr in-place over z buffer ----------------
__global__ __launch_bounds__(256) void k23(float* __restrict__ crt,
    const float* __restrict__ fading, const float* __restrict__ noise,
    const float* __restrict__ bnp,
    const float* __restrict__ pc1w, const float* __restrict__ pc1b,
    const float* __restrict__ pc2s, const float* __restrict__ pc2b,
    const float* __restrict__ pc3w, const float* __restrict__ pc3b,
    const float* __restrict__ pc4w, const float* __restrict__ pc4b,
    const float* __restrict__ pc5s, const float* __restrict__ pc5b,
    const float* __restrict__ plw,  const float* __restrict__ plb,
    int B)
{
    int i = blockIdx.x * 256 + threadIdx.x;
    if (i >= B) return;

    // ---- BN affine on z (in ws) ----
    float zn[16];
    {
        const float4* zp = reinterpret_cast<const float4*>(crt + (size_t)i * 16);
#pragma unroll
        for (int q = 0; q < 4; ++q) {
            float4 v = zp[q];
            zn[4*q+0] = fmaf(v.x, bnp[4*q+0], bnp[16 + 4*q+0]);
            zn[4*q+1] = fmaf(v.y, bnp[4*q+1], bnp[16 + 4*q+1]);
            zn[4*q+2] = fmaf(v.z, bnp[4*q+2], bnp[16 + 4*q+2]);
            zn[4*q+3] = fmaf(v.w, bnp[4*q+3], bnp[16 + 4*q+3]);
        }
    }
    // ---- FIR + noise ----
    float f[6];
    {
        const float2* fp = reinterpret_cast<const float2*>(fading + (size_t)i * 6);
#pragma unroll
        for (int q = 0; q < 3; ++q) { float2 v = fp[q]; f[2*q] = v.x; f[2*q+1] = v.y; }
    }
    float cr[16];
#pragma unroll
    for (int n = 0; n < 8; ++n) {
        float re = f[0]*zn[2*n]   - f[1]*zn[2*n+1];
        float im = f[0]*zn[2*n+1] + f[1]*zn[2*n];
        if (n >= 1) { re += f[2]*zn[2*n-2] - f[3]*zn[2*n-1];
                      im += f[2]*zn[2*n-1] + f[3]*zn[2*n-2]; }
        if (n >= 2) { re += f[4]*zn[2*n-4] - f[5]*zn[2*n-3];
                      im += f[4]*zn[2*n-3] + f[5]*zn[2*n-4]; }
        cr[2*n] = re; cr[2*n+1] = im;
    }
    {
        const float4* np_ = reinterpret_cast<const float4*>(noise + (size_t)i * 16);
#pragma unroll
        for (int q = 0; q < 4; ++q) {
            float4 v = np_[q];
            cr[4*q+0] = fmaf(v.x, NSCALE, cr[4*q+0]);
            cr[4*q+1] = fmaf(v.y, NSCALE, cr[4*q+1]);
            cr[4*q+2] = fmaf(v.z, NSCALE, cr[4*q+2]);
            cr[4*q+3] = fmaf(v.w, NSCALE, cr[4*q+3]);
        }
    }
    // store cr so the rolled g-loop can reload slices with runtime offsets (global idx = no demotion)
    {
        float4* op = reinterpret_cast<float4*>(crt + (size_t)i * 16);
        op[0] = make_float4(cr[0],  cr[1],  cr[2],  cr[3]);
        op[1] = make_float4(cr[4],  cr[5],  cr[6],  cr[7]);
        op[2] = make_float4(cr[8],  cr[9],  cr[10], cr[11]);
        op[3] = make_float4(cr[12], cr[13], cr[14], cr[15]);
    }

    // ---- p-convs (g rolled; all weight reads contiguous) ----
    float p5a[16];
#pragma unroll
    for (int o = 0; o < 16; ++o) p5a[o] = pc5b[o];

#pragma unroll 1
    for (int g = 0; g < 3; ++g) {
        float crg[8];
        {
            const float4* cp = reinterpret_cast<const float4*>(crt + (size_t)i * 16 + 4 * g);
            float4 v0 = cp[0], v1 = cp[1];
            crg[0]=v0.x; crg[1]=v0.y; crg[2]=v0.z; crg[3]=v0.w;
            crg[4]=v1.x; crg[5]=v1.y; crg[6]=v1.z; crg[7]=v1.w;
        }
        float p1c[3][16];
#pragma unroll
        for (int c2 = 0; c2 < 3; ++c2) {
#pragma unroll
            for (int o = 0; o < 16; ++o) {
                float a = pc1b[o];
#pragma unroll
                for (int k = 0; k < 4; ++k) a = fmaf(pc1w[o*4+k], crg[c2+k], a);
                p1c[c2][o] = reluf(a);
            }
        }
        float p2c[2][16];
#pragma unroll
        for (int c2 = 0; c2 < 2; ++c2) {
#pragma unroll
            for (int o = 0; o < 16; ++o) {
                float a = pc2b[o];
#pragma unroll
                for (int ci = 0; ci < 16; ++ci) {
                    a = fmaf(pc2s[      o*16+ci], p1c[c2+0][ci], a);
                    a = fmaf(pc2s[256 + o*16+ci], p1c[c2+1][ci], a);
                }
                p2c[c2][o] = reluf(a);
            }
        }
        float p3[16];
#pragma unroll
        for (int o = 0; o < 16; ++o) {
            float a = pc3b[o];
#pragma unroll
            for (int ci = 0; ci < 16; ++ci) {
                a = fmaf(pc3w[o*32+ci*2+0], p2c[0][ci], a);
                a = fmaf(pc3w[o*32+ci*2+1], p2c[1][ci], a);
            }
            p3[o] = reluf(a);
        }
        float p4[16];
#pragma unroll
        for (int o = 0; o < 16; ++o) {
            float a = pc4b[o];
#pragma unroll
            for (int ci = 0; ci < 16; ++ci) a = fmaf(pc4w[o*16+ci], p3[ci], a);
            p4[o] = reluf(a);
        }
#pragma unroll
        for (int o = 0; o < 16; ++o) {
            float a = p5a[o];
#pragma unroll
            for (int ci = 0; ci < 16; ++ci)
                a = fmaf(pc5s[g*256 + o*16 + ci], p4[ci], a);   // runtime g, contiguous row
            p5a[o] = a;
        }
    }

    float p5r[16];
#pragma unroll
    for (int o = 0; o < 16; ++o) p5r[o] = reluf(p5a[o]);
    float hh[16];
#pragma unroll
    for (int o = 0; o < 16; ++o) {
        float a = plb[o];
#pragma unroll
        for (int ci = 0; ci < 16; ++ci) a = fmaf(plw[o*16+ci], p5r[ci], a);
        hh[o] = a;
    }

    // ---- equalizer (cr still in registers) ----
    float tr[16];
#pragma unroll
    for (int n = 0; n < 8; ++n) {
        float a = cr[2*n], b = cr[2*n+1];
        float c = hh[2*n], d = hh[2*n+1];
        float inv = 1.0f / (c*c + d*d);
        tr[2*n]   = (a*c + b*d) * inv;
        tr[2*n+1] = (b*c - a*d) * inv;
    }
    float4* op = reinterpret_cast<float4*>(crt + (size_t)i * 16);
    op[0] = make_float4(tr[0],  tr[1],  tr[2],  tr[3]);
    op[1] = make_float4(tr[4],  tr[5],  tr[6],  tr[7]);
    op[2] = make_float4(tr[8],  tr[9],  tr[10], tr[11]);
    op[3] = make_float4(tr[12], tr[13], tr[14], tr[15]);
}

// ---------------- k4: d-convs (rolled t-loop, contiguous dl1s) + dl1/dl2/dl3 -> out ----------------
__global__ __launch_bounds__(256) void k4(const float* __restrict__ trt,
    const float* __restrict__ dc1w, const float* __restrict__ dc1b,
    const float* __restrict__ dc2w, const float* __restrict__ dc2b,
    const float* __restrict__ dc3w, const float* __restrict__ dc3b,
    const float* __restrict__ dc4w, const float* __restrict__ dc4b,
    const float* __restrict__ dl1s, const float* __restrict__ dl1b,
    const float* __restrict__ dl2w, const float* __restrict__ dl2b,
    const float* __restrict__ dl3w, const float* __restrict__ dl3b,
    float* __restrict__ out, int B)
{
    int i = blockIdx.x * 256 + threadIdx.x;
    if (i >= B) return;

    float y[16];
#pragma unroll
    for (int o = 0; o < 16; ++o) y[o] = dl1b[o];

#pragma unroll 1
    for (int t = 0; t < 8; ++t) {
        float2 tv = *reinterpret_cast<const float2*>(trt + (size_t)i * 16 + 2 * t);
        float d1a[8], d1b[8];
#pragma unroll
        for (int c = 0; c < 8; ++c) {
            d1a[c] = reluf(fmaf(dc1w[c], tv.x, dc1b[c]));
            d1b[c] = reluf(fmaf(dc1w[c], tv.y, dc1b[c]));
        }
        float d2[8];
#pragma unroll
        for (int c = 0; c < 8; ++c) {
            float a = dc2b[c];
#pragma unroll
            for (int ci = 0; ci < 8; ++ci) {
                a = fmaf(dc2w[c*16+ci*2+0], d1a[ci], a);
                a = fmaf(dc2w[c*16+ci*2+1], d1b[ci], a);
            }
            d2[c] = reluf(a);
        }
        float d3[8];
#pragma unroll
        for (int c = 0; c < 8; ++c) {
            float a = dc3b[c];
#pragma unroll
            for (int ci = 0; ci < 8; ++ci) a = fmaf(dc3w[c*8+ci], d2[ci], a);
            d3[c] = reluf(a);
        }
        float d4[8];
#pragma unroll
        for (int c = 0; c < 8; ++c) {
            float a = dc4b[c];
#pragma unroll
            for (int ci = 0; ci < 8; ++ci) a = fmaf(dc4w[c*8+ci], d3[ci], a);
            d4[c] = reluf(a);
        }
#pragma unroll
        for (int o = 0; o < 16; ++o) {
            float a = y[o];
#pragma unroll
            for (int c = 0; c < 8; ++c) a = fmaf(dl1s[t*128 + o*8 + c], d4[c], a); // contiguous per t
            y[o] = a;
        }
    }
#pragma unroll
    for (int o = 0; o < 16; ++o) y[o] = reluf(y[o]);
    float h2[16];
#pragma unroll
    for (int o = 0; o < 16; ++o) {
        float a = dl2b[o];
#pragma unroll
        for (int ci = 0; ci < 16; ++ci) a = fmaf(dl2w[o*16+ci], y[ci], a);
        h2[o] = eluf(a);
    }
    float o16[16];
#pragma unroll
    for (int o = 0; o < 16; ++o) {
        float a = dl3b[o];
#pragma unroll
        for (int ci = 0; ci < 16; ++ci) a = fmaf(dl3w[o*16+ci], h2[ci], a);
        o16[o] = a;
    }
    float4* op = reinterpret_cast<float4*>(out + (size_t)i * 16);
    op[0] = make_float4(o16[0],  o16[1],  o16[2],  o16[3]);
    op[1] = make_float4(o16[4],  o16[5],  o16[6],  o16[7]);
    op[2] = make_float4(o16[8],  o16[9],  o16[10], o16[11]);
    op[3] = make_float4(o16[12], o16[13], o16[14], o16[15]);
}

extern "C" void kernel_launch(void* const* d_in, const int* in_sizes, int n_in,
                              void* d_out, int out_size, void* d_ws, size_t ws_size,
                              hipStream_t stream)
{
    const float* x      = (const float*)d_in[0];
    const float* noise  = (const float*)d_in[1];
    const float* fading = (const float*)d_in[2];
    const float* ew1  = (const float*)d_in[3];
    const float* eb1  = (const float*)d_in[4];
    const float* ew2  = (const float*)d_in[5];
    const float* eb2  = (const float*)d_in[6];
    const float* bng  = (const float*)d_in[7];
    const float* bnb  = (const float*)d_in[8];
    const float* pc1w = (const float*)d_in[9];
    const float* pc1b = (const float*)d_in[10];
    const float* pc2w = (const float*)d_in[11];
    const float* pc2b = (const float*)d_in[12];
    const float* pc3w = (const float*)d_in[13];
    const float* pc3b = (const float*)d_in[14];
    const float* pc4w = (const float*)d_in[15];
    const float* pc4b = (const float*)d_in[16];
    const float* pc5w = (const float*)d_in[17];
    const float* pc5b = (const float*)d_in[18];
    const float* plw  = (const float*)d_in[19];
    const float* plb  = (const float*)d_in[20];
    const float* dc1w = (const float*)d_in[21];
    const float* dc1b = (const float*)d_in[22];
    const float* dc2w = (const float*)d_in[23];
    const float* dc2b = (const float*)d_in[24];
    const float* dc3w = (const float*)d_in[25];
    const float* dc3b = (const float*)d_in[26];
    const float* dc4w = (const float*)d_in[27];
    const float* dc4b = (const float*)d_in[28];
    const float* dl1w = (const float*)d_in[29];
    const float* dl1b = (const float*)d_in[30];
    const float* dl2w = (const float*)d_in[31];
    const float* dl2b = (const float*)d_in[32];
    const float* dl3w = (const float*)d_in[33];
    const float* dl3b = (const float*)d_in[34];

    int B = in_sizes[0] / 16;
    int nblk = (B + 255) / 256;

    float* partials = (float*)d_ws;                    // nblk*32
    float* bnp  = partials + (size_t)nblk * 32;        // 32
    float* pc2s = bnp + 32;                            // 512
    float* pc5s = pc2s + 512;                          // 768
    float* dl1s = pc5s + 768;                          // 1024
    float* crt  = dl1s + 1024;                         // B*16 (z -> cr -> tr in-place)

    kW<<<1, 256, 0, stream>>>(pc2w, pc5w, dl1w, pc2s, pc5s, dl1s);
    kA<<<nblk, 256, 0, stream>>>(x, ew1, eb1, ew2, eb2, partials, crt, B);
    kB<<<1, 256, 0, stream>>>(partials, nblk, B, bng, bnb, bnp);
    k23<<<nblk, 256, 0, stream>>>(crt, fading, noise, bnp,
                                  pc1w, pc1b, pc2s, pc2b, pc3w, pc3b, pc4w, pc4b, pc5s, pc5b,
                                  plw, plb, B);
    k4<<<nblk, 256, 0, stream>>>(crt,
                                 dc1w, dc1b, dc2w, dc2b, dc3w, dc3b, dc4w, dc4b,
                                 dl1s, dl1b, dl2w, dl2b, dl3w, dl3b,
                                 (float*)d_out, B);
}